// Round 1
// baseline (419.119 us; speedup 1.0000x reference)
//
#include <hip/hip_runtime.h>
#include <stdint.h>
#include <stddef.h>

// BitLinear on MI355X: out[m,o] = sx[m] * sw * sum_i qx[m,i]*qw[o,i]
//   qx: per-row int8 absmax fake-quant of x, qw: ternary {-1,0,1} from absmean.
// Integer inner product is exact; only scales carry float rounding.

#define K_DIM 4096
#define M_DIM 8192
#define N_DIM 4096

typedef int v4i __attribute__((ext_vector_type(4)));

// ---------------- async global->LDS (16B per lane, wave-uniform LDS base) ----
__device__ __forceinline__ void async_copy16(void* lds, const void* g) {
  __builtin_amdgcn_global_load_lds(
      (const __attribute__((address_space(1))) unsigned int*)g,
      (__attribute__((address_space(3))) unsigned int*)lds,
      16, 0, 0);
}

// ---------------- kernel 1: per-block partial sums of |w| (double) ----------
__global__ void k_wsum(const float* __restrict__ w, double* __restrict__ partials) {
  // 1024 blocks x 256 threads over 4194304 float4
  const float4* w4 = (const float4*)w;
  int tid = blockIdx.x * 256 + threadIdx.x;          // 262144 threads
  double s = 0.0;
  for (int i = tid; i < 4194304; i += 262144) {      // 16 iters
    float4 v = w4[i];
    s += (double)fabsf(v.x) + (double)fabsf(v.y) +
         (double)fabsf(v.z) + (double)fabsf(v.w);
  }
  for (int off = 32; off > 0; off >>= 1) s += __shfl_down(s, off);
  __shared__ double lsum[4];
  int lane = threadIdx.x & 63, wid = threadIdx.x >> 6;
  if (lane == 0) lsum[wid] = s;
  __syncthreads();
  if (threadIdx.x == 0)
    partials[blockIdx.x] = lsum[0] + lsum[1] + lsum[2] + lsum[3];
}

// ---------------- kernel 1b: reduce partials -> float scale -----------------
__global__ void k_wscale(const double* __restrict__ partials, float* __restrict__ wscale) {
  double s = 0.0;
  for (int i = threadIdx.x; i < 1024; i += 256) s += partials[i];
  for (int off = 32; off > 0; off >>= 1) s += __shfl_down(s, off);
  __shared__ double lsum[4];
  int lane = threadIdx.x & 63, wid = threadIdx.x >> 6;
  if (lane == 0) lsum[wid] = s;
  __syncthreads();
  if (threadIdx.x == 0) {
    double tot = lsum[0] + lsum[1] + lsum[2] + lsum[3];
    *wscale = (float)(tot / 16777216.0);             // exact-ish mean(|w|)
  }
}

// ---------------- kernel 2: ternary-quantize weight -> int8 -----------------
__global__ void k_wq(const float* __restrict__ w, const float* __restrict__ wscale,
                     char* __restrict__ qw) {
  float d = *wscale + 1e-8f;                         // matches ref divisor
  const float4* w4 = (const float4*)w;
  int* q4 = (int*)qw;
  int tid = blockIdx.x * 256 + threadIdx.x;          // 2048*256 = 524288 threads
  for (int i = tid; i < 4194304; i += 524288) {      // 8 iters
    float4 v = w4[i];
    // true fp32 division + rint (half-even) to match np bitwise
    int a = (int)fmaxf(fminf(rintf(v.x / d), 1.f), -1.f);
    int b = (int)fmaxf(fminf(rintf(v.y / d), 1.f), -1.f);
    int c = (int)fmaxf(fminf(rintf(v.z / d), 1.f), -1.f);
    int e = (int)fmaxf(fminf(rintf(v.w / d), 1.f), -1.f);
    q4[i] = (a & 255) | ((b & 255) << 8) | ((c & 255) << 16) | ((e & 255) << 24);
  }
}

// ---------------- kernel 3: per-row activation quantize -> int8 + scale -----
__global__ void k_xq(const float* __restrict__ x, char* __restrict__ qx,
                     float* __restrict__ sx) {
  int row = blockIdx.x;                               // 8192 rows
  const float4* xr = (const float4*)(x + (size_t)row * K_DIM);
  float4 v[4];
  float m = 0.f;
#pragma unroll
  for (int c = 0; c < 4; c++) {
    v[c] = xr[threadIdx.x + c * 256];
    m = fmaxf(m, fmaxf(fmaxf(fabsf(v[c].x), fabsf(v[c].y)),
                       fmaxf(fabsf(v[c].z), fabsf(v[c].w))));
  }
  for (int off = 32; off > 0; off >>= 1) m = fmaxf(m, __shfl_down(m, off));
  __shared__ float lm[4];
  __shared__ float bscale;
  int lane = threadIdx.x & 63, wid = threadIdx.x >> 6;
  if (lane == 0) lm[wid] = m;
  __syncthreads();
  if (threadIdx.x == 0) {
    float mm = fmaxf(fmaxf(lm[0], lm[1]), fmaxf(lm[2], lm[3]));
    float sc = fmaxf(mm / 127.0f, 1e-8f);            // true division like ref
    bscale = sc;
    sx[row] = sc;
  }
  __syncthreads();
  float sc = bscale;
  int* q4 = (int*)(qx + (size_t)row * K_DIM);
#pragma unroll
  for (int c = 0; c < 4; c++) {
    int a = (int)fmaxf(fminf(rintf(v[c].x / sc), 127.f), -127.f);
    int b = (int)fmaxf(fminf(rintf(v[c].y / sc), 127.f), -127.f);
    int cc = (int)fmaxf(fminf(rintf(v[c].z / sc), 127.f), -127.f);
    int e = (int)fmaxf(fminf(rintf(v[c].w / sc), 127.f), -127.f);
    q4[threadIdx.x + c * 256] = (a & 255) | ((b & 255) << 8) | ((cc & 255) << 16) | ((e & 255) << 24);
  }
}

// ---------------- kernel 4: int8 MFMA GEMM (m97 structure) ------------------
// 128x128 C-tile per block, 256 threads = 4 waves (2x2 of 64x64 quadrants),
// BK = 64 int8 (one mfma_i32_16x16x64_i8 per K-chunk), global_load_lds x16B.
__global__ void k_gemm(const char* __restrict__ qx, const char* __restrict__ qw,
                       const float* __restrict__ sx, const float* __restrict__ wscale,
                       float* __restrict__ out) {
  __shared__ char ldsA[128 * 64];
  __shared__ char ldsB[128 * 64];

  const int bn = blockIdx.x & 31;          // 32 tiles along N
  const int bm = blockIdx.x >> 5;          // 64 tiles along M
  const int rowBase = bm * 128;
  const int colBase = bn * 128;
  const int tid = threadIdx.x;
  const int lane = tid & 63;
  const int wave = tid >> 6;
  const int wr = wave >> 1, wc = wave & 1;

  v4i acc[4][4] = {};

  // staging: wave handles 2 chunks of A (2KB) and 2 of B; lane l covers
  // lds offset l*16 -> row (l>>2), koff (l&3)*16 within its 16-row chunk.
  const int sRow = wave * 32 + (lane >> 2);
  const int sK = (lane & 3) * 16;
  const char* gA0 = qx + (size_t)(rowBase + sRow) * K_DIM + sK;
  const char* gA1 = gA0 + 16 * K_DIM;
  const char* gB0 = qw + (size_t)(colBase + sRow) * K_DIM + sK;
  const char* gB1 = gB0 + 16 * K_DIM;
  char* lA0 = ldsA + wave * 2048;          // wave-uniform LDS bases
  char* lA1 = lA0 + 1024;
  char* lB0 = ldsB + wave * 2048;
  char* lB1 = lB0 + 1024;

  // compute-phase LDS addresses (verified m97 fragment geometry, i8 bytes)
  const int kseg = (lane >> 4) * 16;
  const char* aPtr = ldsA + (wr * 64 + (lane & 15)) * 64 + kseg;
  const char* bPtr = ldsB + (wc * 64 + (lane & 15)) * 64 + kseg;

  for (int kb = 0; kb < K_DIM / 64; kb++) {
    if (kb) __syncthreads();
    const int goff = kb * 64;
    async_copy16(lA0, gA0 + goff);
    async_copy16(lA1, gA1 + goff);
    async_copy16(lB0, gB0 + goff);
    async_copy16(lB1, gB1 + goff);
    __syncthreads();                       // drains vmcnt for the DMA

    v4i a[4], b[4];
#pragma unroll
    for (int t = 0; t < 4; t++) {
      a[t] = *(const v4i*)(aPtr + t * 16 * 64);
      b[t] = *(const v4i*)(bPtr + t * 16 * 64);
    }
#pragma unroll
    for (int mt = 0; mt < 4; mt++)
#pragma unroll
      for (int nt = 0; nt < 4; nt++)
        acc[mt][nt] = __builtin_amdgcn_mfma_i32_16x16x64_i8(a[mt], b[nt], acc[mt][nt], 0, 0, 0);
  }

  // epilogue: C/D 16x16 layout col=lane&15, row=(lane>>4)*4+reg
  const float sw = *wscale;
  const int col0 = colBase + wc * 64 + (lane & 15);
  const int row0 = rowBase + wr * 64 + (lane >> 4) * 4;
#pragma unroll
  for (int mt = 0; mt < 4; mt++) {
#pragma unroll
    for (int r = 0; r < 4; r++) {
      const int row = row0 + mt * 16 + r;
      const float s = sx[row] * sw;
#pragma unroll
      for (int nt = 0; nt < 4; nt++)
        out[(size_t)row * N_DIM + col0 + nt * 16] = (float)acc[mt][nt][r] * s;
    }
  }
}

// ---------------- launcher ---------------------------------------------------
extern "C" void kernel_launch(void* const* d_in, const int* in_sizes, int n_in,
                              void* d_out, int out_size, void* d_ws, size_t ws_size,
                              hipStream_t stream) {
  const float* x = (const float*)d_in[0];   // [2,4096,4096]
  const float* w = (const float*)d_in[1];   // [4096,4096]
  float* out = (float*)d_out;               // [2,4096,4096]
  char* ws = (char*)d_ws;

  // ws layout (needs ~48.1 MiB):
  double* partials = (double*)ws;                  // 1024 doubles  @ 0
  float* wscale    = (float*)(ws + 8192);          // 1 float       @ 8192
  float* sx        = (float*)(ws + 8448);          // 8192 floats   @ 8448
  char*  qw        = ws + 41472;                   // 16 MiB        @ 41472
  char*  qx        = ws + 41472 + 16777216;        // 32 MiB

  k_wsum  <<<1024, 256, 0, stream>>>(w, partials);
  k_wscale<<<   1, 256, 0, stream>>>(partials, wscale);
  k_wq    <<<2048, 256, 0, stream>>>(w, wscale, qw);
  k_xq    <<<8192, 256, 0, stream>>>(x, qx, sx);
  k_gemm  <<<64 * 32, 256, 0, stream>>>(qx, qw, sx, wscale, out);
}